// Round 2
// baseline (475.660 us; speedup 1.0000x reference)
//
#include <hip/hip_runtime.h>

// EventMessagePassingEdge: per-edge 2-layer MLP with gathered node features.
//   evt[e] = [h[src[e]], e_h[e], h[dst[e]]]           (192 fp32)
//   x      = evt @ W1 + b1                            (64)
//   out    = relu([x, ext[e]] @ W2 + b2)              (64 fp32)
// R2: layer-1 A-fragments loaded DIRECTLY from global (lane = 32B contiguous
// chunk of one edge row), packed to bf16 in regs -> MFMA. No LDS staging for
// A. Only the x C->A roundtrip uses LDS (2KB/wave). LDS 60->44KB => 3
// blocks/CU (12 waves/CU vs 8). W1/W2 B-frags staged once per block.

typedef __attribute__((ext_vector_type(8))) short bf16x8;
typedef __attribute__((ext_vector_type(4))) float f32x4;

__device__ __forceinline__ short f2bf(float f) {
  // round-to-nearest-even fp32 -> bf16
  unsigned u = __builtin_bit_cast(unsigned, f);
  u = (u + 0x7FFFu + ((u >> 16) & 1u)) >> 16;
  return (short)u;
}

__device__ __forceinline__ bf16x8 pack8(float4 a, float4 b) {
  bf16x8 r;
  r[0] = f2bf(a.x); r[1] = f2bf(a.y); r[2] = f2bf(a.z); r[3] = f2bf(a.w);
  r[4] = f2bf(b.x); r[5] = f2bf(b.y); r[6] = f2bf(b.z); r[7] = f2bf(b.w);
  return r;
}

// LDS layout (shorts):
//   [0,     12288)  W1 frags: slot s = (kc*4+nt)*64 + lane, 8 bf16 each
//   [12288, 18432)  W2 frags: same scheme (kc 0..2)
//   [18432, 22528)  per-wave x roundtrip buffer, 1024 shorts (2 KB) per wave
//     x slot = kc*64 + quad*16 + m (kc 0..1), holds x[m][kc*32+quad*8+j]

__global__ __launch_bounds__(256, 3) void edge_mp_kernel(
    const float* __restrict__ h, const float* __restrict__ e_h,
    const float* __restrict__ ext, const float* __restrict__ W1,
    const float* __restrict__ b1, const float* __restrict__ W2,
    const float* __restrict__ b2, const int* __restrict__ src,
    const int* __restrict__ dst, float* __restrict__ out, int E) {
  __shared__ __align__(16) short lds[22528];
  const int tid = threadIdx.x;
  const int l = tid & 63;   // lane
  const int wid = tid >> 6; // wave in block
  const int i = l & 15;     // MFMA i (col of C / row of A)
  const int q = l >> 4;     // MFMA quad

  // ---- stage W1 fragments (1536 slots, b128 writes) ----
  for (int s = tid; s < 1536; s += 256) {
    int kc = s >> 8, nt = (s >> 6) & 3, ll = s & 63;
    int k0 = kc * 32 + ((ll >> 4) * 8), n = nt * 16 + (ll & 15);
    bf16x8 w;
#pragma unroll
    for (int j = 0; j < 8; ++j) w[j] = f2bf(W1[(k0 + j) * 64 + n]);
    *(bf16x8*)&lds[s * 8] = w;
  }
  // ---- stage W2 fragments (768 slots) ----
  for (int s = tid; s < 768; s += 256) {
    int kc = s >> 8, nt = (s >> 6) & 3, ll = s & 63;
    int k0 = kc * 32 + ((ll >> 4) * 8), n = nt * 16 + (ll & 15);
    bf16x8 w;
#pragma unroll
    for (int j = 0; j < 8; ++j) w[j] = f2bf(W2[(k0 + j) * 64 + n]);
    *(bf16x8*)&lds[12288 + s * 8] = w;
  }
  __syncthreads();

  float b1v[4], b2v[4];
#pragma unroll
  for (int nt = 0; nt < 4; ++nt) {
    b1v[nt] = b1[nt * 16 + i];
    b2v[nt] = b2[nt * 16 + i];
  }

  short* xb = &lds[18432 + wid * 1024];

  // prefetch indices for it=0
  int e_nxt = blockIdx.x * 256 + wid * 16 + i;
  if (e_nxt >= E) e_nxt = E - 1;
  int sI_nxt = src[e_nxt], dI_nxt = dst[e_nxt];

  for (int it = 0; it < 4; ++it) {
    const int e0 = blockIdx.x * 256 + it * 64 + wid * 16;
    if (e0 >= E) break;
    const int e = e_nxt;
    const int sI = sI_nxt, dI = dI_nxt;
    if (it < 3) {
      int en = e0 + 64 + i;
      if (en >= E) en = E - 1;
      e_nxt = en;
      sI_nxt = src[en];
      dI_nxt = dst[en];
    }

    // ---- direct-global A-fragment loads: lane = 32B chunk of edge row ----
    const float* ps = h + (size_t)sI * 64 + q * 8;
    const float* pe = e_h + (size_t)e * 64 + q * 8;
    const float* pd = h + (size_t)dI * 64 + q * 8;
    const float* px = ext + (size_t)e * 32 + q * 8;
    float4 ld[12];
    ld[0] = *(const float4*)(ps);      ld[1] = *(const float4*)(ps + 4);
    ld[2] = *(const float4*)(ps + 32); ld[3] = *(const float4*)(ps + 36);
    ld[4] = *(const float4*)(pe);      ld[5] = *(const float4*)(pe + 4);
    ld[6] = *(const float4*)(pe + 32); ld[7] = *(const float4*)(pe + 36);
    ld[8] = *(const float4*)(pd);      ld[9] = *(const float4*)(pd + 4);
    ld[10] = *(const float4*)(pd + 32); ld[11] = *(const float4*)(pd + 36);
    float4 x0 = *(const float4*)(px);
    float4 x1 = *(const float4*)(px + 4);

    // ---- layer 1: 6 kc x 4 nt MFMAs, A from regs, B from LDS ----
    f32x4 acc[4] = {{0.f, 0.f, 0.f, 0.f}, {0.f, 0.f, 0.f, 0.f},
                    {0.f, 0.f, 0.f, 0.f}, {0.f, 0.f, 0.f, 0.f}};
#pragma unroll
    for (int kc = 0; kc < 6; ++kc) {
      bf16x8 a = pack8(ld[kc * 2], ld[kc * 2 + 1]);
#pragma unroll
      for (int nt = 0; nt < 4; ++nt) {
        bf16x8 b = *(const bf16x8*)&lds[((kc * 4 + nt) * 64 + l) * 8];
        acc[nt] = __builtin_amdgcn_mfma_f32_16x16x32_bf16(a, b, acc[nt], 0, 0, 0);
      }
    }

    // ---- x (C-layout) + b1 -> bf16 -> A-layout LDS roundtrip ----
#pragma unroll
    for (int nt = 0; nt < 4; ++nt) {
      const int n = nt * 16 + i;
      const int slotbase = (n >> 5) * 64 + ((n & 31) >> 3) * 16;
      const int j = n & 7;
#pragma unroll
      for (int r = 0; r < 4; ++r) {
        xb[(slotbase + q * 4 + r) * 8 + j] = f2bf(acc[nt][r] + b1v[nt]);
      }
    }

    // ---- layer 2: kc 0,1 from LDS roundtrip; kc 2 = ext direct ----
    f32x4 acc2[4] = {{0.f, 0.f, 0.f, 0.f}, {0.f, 0.f, 0.f, 0.f},
                     {0.f, 0.f, 0.f, 0.f}, {0.f, 0.f, 0.f, 0.f}};
#pragma unroll
    for (int kc = 0; kc < 2; ++kc) {
      bf16x8 a = *(const bf16x8*)&xb[(kc * 64 + l) * 8];
#pragma unroll
      for (int nt = 0; nt < 4; ++nt) {
        bf16x8 b = *(const bf16x8*)&lds[12288 + ((kc * 4 + nt) * 64 + l) * 8];
        acc2[nt] =
            __builtin_amdgcn_mfma_f32_16x16x32_bf16(a, b, acc2[nt], 0, 0, 0);
      }
    }
    {
      bf16x8 a = pack8(x0, x1);
#pragma unroll
      for (int nt = 0; nt < 4; ++nt) {
        bf16x8 b = *(const bf16x8*)&lds[12288 + ((2 * 4 + nt) * 64 + l) * 8];
        acc2[nt] =
            __builtin_amdgcn_mfma_f32_16x16x32_bf16(a, b, acc2[nt], 0, 0, 0);
      }
    }

    // ---- epilogue: +b2, relu, store fp32 (C-layout) ----
#pragma unroll
    for (int nt = 0; nt < 4; ++nt) {
      const int n = nt * 16 + i;
#pragma unroll
      for (int r = 0; r < 4; ++r) {
        const int er = e0 + q * 4 + r;
        if (er < E) {
          out[(size_t)er * 64 + n] = fmaxf(acc2[nt][r] + b2v[nt], 0.f);
        }
      }
    }
  }
}

extern "C" void kernel_launch(void* const* d_in, const int* in_sizes, int n_in,
                              void* d_out, int out_size, void* d_ws,
                              size_t ws_size, hipStream_t stream) {
  const float* h = (const float*)d_in[0];
  const float* e_h = (const float*)d_in[1];
  const float* ext = (const float*)d_in[2];
  const float* W1 = (const float*)d_in[3];
  const float* b1 = (const float*)d_in[4];
  const float* W2 = (const float*)d_in[5];
  const float* b2 = (const float*)d_in[6];
  const int* src = (const int*)d_in[7];
  const int* dst = (const int*)d_in[8];
  float* out = (float*)d_out;
  const int E = in_sizes[7];  // 800000
  const int blocks = (E + 255) / 256;
  hipLaunchKernelGGL(edge_mp_kernel, dim3(blocks), dim3(256), 0, stream, h, e_h,
                     ext, W1, b1, W2, b2, src, dst, out, E);
}